// Round 1
// baseline (748.336 us; speedup 1.0000x reference)
//
#include <hip/hip_runtime.h>

typedef _Float16 f16;
typedef _Float16 f16x8 __attribute__((ext_vector_type(8)));
typedef float f32x4 __attribute__((ext_vector_type(4)));

#define CIN 28
#define TT 8
#define HW 16384

// gate pre-scales folded into weights: sigmoid(x)=rcp(1+exp2(-x*log2e)),
// tanh(x)=1-2*rcp(1+exp2(x*2*log2e))
#define S_SIG  (-1.44269504088896341f)
#define S_TANH ( 2.88539008177792681f)

// workspace layout (bytes)
#define WS_WX    0        // f16 [256][32]  folded Wih1*W_red (+denorm scales, gate scale)
#define WS_WHH1  16384    // f16 [256][64]
#define WS_W21   49152    // f16 [256][64]  folded Wih2*Wc1
#define WS_WHH2  81920    // f16 [256][64]
#define WS_BX    114688   // f32 [256]
#define WS_B2    115712   // f32 [256]
#define WS_WH    116736   // f32 [64]       folded W_head*Wc2
#define WS_BH    116992   // f32 [1]

__device__ __forceinline__ float sig_pre(float v) {   // v already = -x*log2e
  return __builtin_amdgcn_rcpf(1.f + __builtin_amdgcn_exp2f(v));
}
__device__ __forceinline__ float tanh_pre(float v) {  // v already = x*2*log2e
  return 1.f - 2.f * __builtin_amdgcn_rcpf(1.f + __builtin_amdgcn_exp2f(v));
}
__device__ __forceinline__ float tanh_raw(float x) {
  return tanh_pre(x * S_TANH);
}

__global__ __launch_bounds__(256) void prep_kernel(
    const float* __restrict__ W_red, const float* __restrict__ b_red,
    const float* __restrict__ Wih1, const float* __restrict__ Whh1,
    const float* __restrict__ bih1, const float* __restrict__ bhh1,
    const float* __restrict__ Wc1,  const float* __restrict__ bc1,
    const float* __restrict__ Wih2, const float* __restrict__ Whh2,
    const float* __restrict__ bih2, const float* __restrict__ bhh2,
    const float* __restrict__ Wc2,  const float* __restrict__ bc2,
    const float* __restrict__ W_head, const float* __restrict__ b_head,
    unsigned char* __restrict__ ws)
{
  const int g = threadIdx.x;   // 0..255 gate row
  f16* WxH   = (f16*)(ws + WS_WX);
  f16* Whh1H = (f16*)(ws + WS_WHH1);
  f16* W21H  = (f16*)(ws + WS_W21);
  f16* Whh2H = (f16*)(ws + WS_WHH2);
  float* BX  = (float*)(ws + WS_BX);
  float* B2  = (float*)(ws + WS_B2);
  float* WHp = (float*)(ws + WS_WH);
  float* BHp = (float*)(ws + WS_BH);

  const float sc = ((g >> 6) == 2) ? S_TANH : S_SIG;  // gate g uses tanh

  // Wx row g = Wih1[g,:] @ W_red  (+ u/v denorm fold)
  float wxrow[CIN];
  for (int c = 0; c < CIN; ++c) {
    float s = 0.f;
    for (int r = 0; r < 24; ++r) s += Wih1[g*24 + r] * W_red[r*28 + c];
    wxrow[c] = s;
  }
  float bx = bih1[g] + bhh1[g];
  for (int r = 0; r < 24; ++r) bx += Wih1[g*24 + r] * b_red[r];
  bx += wxrow[11] * 0.02f + wxrow[12] * (-0.01f);   // MU_U, MU_V
  wxrow[11] *= 0.15f;                                // SD_U
  wxrow[12] *= 0.12f;                                // SD_V
  for (int c = 0; c < 32; ++c)
    WxH[g*32 + c] = (c < CIN) ? (f16)(wxrow[c] * sc) : (f16)0.f;
  BX[g] = bx * sc;

  for (int k = 0; k < 64; ++k) Whh1H[g*64 + k] = (f16)(Whh1[g*64 + k] * sc);

  // W21 row g = Wih2[g,:] @ Wc1
  float b2v = bih2[g] + bhh2[g];
  for (int m = 0; m < 64; ++m) b2v += Wih2[g*64 + m] * bc1[m];
  B2[g] = b2v * sc;
  for (int k = 0; k < 64; ++k) {
    float s = 0.f;
    for (int m = 0; m < 64; ++m) s += Wih2[g*64 + m] * Wc1[m*64 + k];
    W21H[g*64 + k]  = (f16)(s * sc);
    Whh2H[g*64 + k] = (f16)(Whh2[g*64 + k] * sc);
  }
  if (g < 64) {
    float s = 0.f;
    for (int m = 0; m < 64; ++m) s += W_head[m] * Wc2[m*64 + g];
    WHp[g] = s;
  }
  if (g == 0) {
    float s = b_head[0];
    for (int m = 0; m < 64; ++m) s += W_head[m] * bc2[m];
    BHp[0] = s;
  }
}

// Main: 64 pixels/block, 4 waves; wave w owns hidden cols [16w,16w+16) for all
// 64 pixels; weights' B-fragments live in registers; h1/h2 double-buffered LDS.
__global__ __launch_bounds__(256, 2) void convlstm_main(
    const float* __restrict__ x, const unsigned char* __restrict__ ws,
    float* __restrict__ out)
{
  __shared__ __align__(16) f16 xs[64 * 40];          // [pixel][ch], stride 40
  __shared__ __align__(16) f16 h1buf[2][64 * 72];    // [pixel][hid], stride 72
  __shared__ __align__(16) f16 h2buf[2][64 * 72];
  __shared__ __align__(16) f16 wxs[256 * 32];        // Wx staged (B-frags per step)
  __shared__ float outpart[64][4];

  const int tid  = threadIdx.x;
  const int lane = tid & 63;
  const int wv   = tid >> 6;     // wave 0..3
  const int cl   = lane & 15;    // MFMA "lane&15"
  const int qd   = lane >> 4;    // MFMA quad

  const f16* Whh1G = (const f16*)(ws + WS_WHH1);
  const f16* W21G  = (const f16*)(ws + WS_W21);
  const f16* Whh2G = (const f16*)(ws + WS_WHH2);
  const float* BX  = (const float*)(ws + WS_BX);
  const float* B2  = (const float*)(ws + WS_B2);

  // ---- load per-wave weight fragments into registers (B layout: [n][k]) ----
  f16x8 whh1f[4][2], w21f[4][2], whh2f[4][2];
  float bxr[4], b2r[4];
#pragma unroll
  for (int P = 0; P < 4; ++P) {                      // i,f,g,o
    const int gr = 64*P + 16*wv + cl;
#pragma unroll
    for (int s = 0; s < 2; ++s) {
      whh1f[P][s] = *(const f16x8*)(Whh1G + gr*64 + s*32 + qd*8);
      w21f[P][s]  = *(const f16x8*)(W21G  + gr*64 + s*32 + qd*8);
      whh2f[P][s] = *(const f16x8*)(Whh2G + gr*64 + s*32 + qd*8);
    }
    bxr[P] = BX[gr];
    b2r[P] = B2[gr];
  }
  const float whc   = ((const float*)(ws + WS_WH))[16*wv + cl];
  const float bhead = *((const float*)(ws + WS_BH));

  // stage Wx into LDS; zero t=0 h buffers
  {
    const uint4* src = (const uint4*)(ws + WS_WX);
    uint4* dst = (uint4*)wxs;
#pragma unroll
    for (int i = tid; i < 1024; i += 256) dst[i] = src[i];
    unsigned* z1 = (unsigned*)&h1buf[0][0];
    unsigned* z2 = (unsigned*)&h2buf[0][0];
#pragma unroll
    for (int i = tid; i < 2304; i += 256) { z1[i] = 0u; z2[i] = 0u; }
  }

  const int gpix = blockIdx.x * 64;
  const float* xb = x + (size_t)(gpix >> 14) * (TT * CIN * HW) + (gpix & (HW - 1));

  float c1s[4][4], c2s[4][4];
#pragma unroll
  for (int a = 0; a < 4; ++a)
#pragma unroll
    for (int b = 0; b < 4; ++b) { c1s[a][b] = 0.f; c2s[a][b] = 0.f; }

  for (int t = 0; t < TT; ++t) {
    // ---- stage x_t : coalesced global load, transpose to [pixel][ch] fp16 ----
    const float* xt = xb + (size_t)t * (CIN * HW);
#pragma unroll
    for (int e = tid; e < 2048; e += 256) {
      const int ch = e >> 6, p = e & 63;
      xs[p*40 + ch] = (ch < CIN) ? (f16)xt[ch*HW + p] : (f16)0.f;
    }
    __syncthreads();

    const f16* h1r = h1buf[t & 1];
    const f16* h2r = h2buf[t & 1];
    f16* h1w = h1buf[(t + 1) & 1];
    f16* h2w = h2buf[(t + 1) & 1];

    f32x4 acc[4][4];
    // ---- gates1 = Wx*x + Whh1*h1 + b ----
#pragma unroll
    for (int mb = 0; mb < 4; ++mb) {
      const int p = 16*mb + cl;
      const f16x8 ax  = *(const f16x8*)(xs  + p*40 + qd*8);
      const f16x8 ah0 = *(const f16x8*)(h1r + p*72 + qd*8);
      const f16x8 ah1 = *(const f16x8*)(h1r + p*72 + 32 + qd*8);
#pragma unroll
      for (int P = 0; P < 4; ++P) {
        const f16x8 wxf = *(const f16x8*)(wxs + (64*P + 16*wv + cl)*32 + qd*8);
        f32x4 a = { bxr[P], bxr[P], bxr[P], bxr[P] };
        a = __builtin_amdgcn_mfma_f32_16x16x32_f16(ax,  wxf,         a, 0, 0, 0);
        a = __builtin_amdgcn_mfma_f32_16x16x32_f16(ah0, whh1f[P][0], a, 0, 0, 0);
        a = __builtin_amdgcn_mfma_f32_16x16x32_f16(ah1, whh1f[P][1], a, 0, 0, 0);
        acc[mb][P] = a;
      }
    }
    // ---- LSTM1 activations; write h1_new (D layout: row=4*qd+r, col=cl) ----
#pragma unroll
    for (int mb = 0; mb < 4; ++mb) {
#pragma unroll
      for (int r = 0; r < 4; ++r) {
        const float ig = sig_pre(acc[mb][0][r]);
        const float fg = sig_pre(acc[mb][1][r]);
        const float gg = tanh_pre(acc[mb][2][r]);
        const float og = sig_pre(acc[mb][3][r]);
        const float cn = fg * c1s[mb][r] + ig * gg;
        c1s[mb][r] = cn;
        const float hn = og * tanh_raw(cn);
        h1w[(16*mb + 4*qd + r)*72 + 16*wv + cl] = (f16)hn;
      }
    }
    __syncthreads();

    // ---- gates2 = W21*h1_new + Whh2*h2 + b ----
#pragma unroll
    for (int mb = 0; mb < 4; ++mb) {
      const int p = 16*mb + cl;
      const f16x8 an0 = *(const f16x8*)(h1w + p*72 + qd*8);
      const f16x8 an1 = *(const f16x8*)(h1w + p*72 + 32 + qd*8);
      const f16x8 a20 = *(const f16x8*)(h2r + p*72 + qd*8);
      const f16x8 a21 = *(const f16x8*)(h2r + p*72 + 32 + qd*8);
#pragma unroll
      for (int P = 0; P < 4; ++P) {
        f32x4 a = { b2r[P], b2r[P], b2r[P], b2r[P] };
        a = __builtin_amdgcn_mfma_f32_16x16x32_f16(an0, w21f[P][0],  a, 0, 0, 0);
        a = __builtin_amdgcn_mfma_f32_16x16x32_f16(an1, w21f[P][1],  a, 0, 0, 0);
        a = __builtin_amdgcn_mfma_f32_16x16x32_f16(a20, whh2f[P][0], a, 0, 0, 0);
        a = __builtin_amdgcn_mfma_f32_16x16x32_f16(a21, whh2f[P][1], a, 0, 0, 0);
        acc[mb][P] = a;
      }
    }
    // ---- LSTM2 activations; write h2_new; head partials at t==7 ----
#pragma unroll
    for (int mb = 0; mb < 4; ++mb) {
#pragma unroll
      for (int r = 0; r < 4; ++r) {
        const float ig = sig_pre(acc[mb][0][r]);
        const float fg = sig_pre(acc[mb][1][r]);
        const float gg = tanh_pre(acc[mb][2][r]);
        const float og = sig_pre(acc[mb][3][r]);
        const float cn = fg * c2s[mb][r] + ig * gg;
        c2s[mb][r] = cn;
        const float hn = og * tanh_raw(cn);
        h2w[(16*mb + 4*qd + r)*72 + 16*wv + cl] = (f16)hn;
        if (t == TT - 1) {
          float pa = hn * whc;
          pa += __shfl_xor(pa, 1, 64);
          pa += __shfl_xor(pa, 2, 64);
          pa += __shfl_xor(pa, 4, 64);
          pa += __shfl_xor(pa, 8, 64);
          if (cl == 0) outpart[16*mb + 4*qd + r][wv] = pa;
        }
      }
    }
    __syncthreads();
  }

  if (tid < 64) {
    out[gpix + tid] = outpart[tid][0] + outpart[tid][1] +
                      outpart[tid][2] + outpart[tid][3] + bhead;
  }
}

extern "C" void kernel_launch(void* const* d_in, const int* in_sizes, int n_in,
                              void* d_out, int out_size, void* d_ws, size_t ws_size,
                              hipStream_t stream) {
  const float* x      = (const float*)d_in[0];
  const float* W_red  = (const float*)d_in[1];
  const float* b_red  = (const float*)d_in[2];
  const float* Wih1   = (const float*)d_in[3];
  const float* Whh1   = (const float*)d_in[4];
  const float* bih1   = (const float*)d_in[5];
  const float* bhh1   = (const float*)d_in[6];
  const float* Wc1    = (const float*)d_in[7];
  const float* bc1    = (const float*)d_in[8];
  const float* Wih2   = (const float*)d_in[9];
  const float* Whh2   = (const float*)d_in[10];
  const float* bih2   = (const float*)d_in[11];
  const float* bhh2   = (const float*)d_in[12];
  const float* Wc2    = (const float*)d_in[13];
  const float* bc2    = (const float*)d_in[14];
  const float* W_head = (const float*)d_in[15];
  const float* b_head = (const float*)d_in[16];

  prep_kernel<<<1, 256, 0, stream>>>(W_red, b_red, Wih1, Whh1, bih1, bhh1,
                                     Wc1, bc1, Wih2, Whh2, bih2, bhh2,
                                     Wc2, bc2, W_head, b_head,
                                     (unsigned char*)d_ws);
  convlstm_main<<<2048, 256, 0, stream>>>(x, (const unsigned char*)d_ws,
                                          (float*)d_out);
}

// Round 2
// 620.086 us; speedup vs baseline: 1.2068x; 1.2068x over previous
//
#include <hip/hip_runtime.h>

typedef _Float16 f16;
typedef _Float16 f16x8 __attribute__((ext_vector_type(8)));
typedef float f32x4 __attribute__((ext_vector_type(4)));

#define CIN 28
#define TT 8
#define HW 16384

// gate pre-scales folded into weights: sigmoid(x)=rcp(1+exp2(-x*log2e)),
// tanh(x)=1-2*rcp(1+exp2(x*2*log2e))
#define S_SIG  (-1.44269504088896341f)
#define S_TANH ( 2.88539008177792681f)

// workspace layout (bytes)
#define WS_WX    0        // f16 [256][32]  folded Wih1*W_red (+denorm scales, gate scale)
#define WS_WHH1  16384    // f16 [256][64]
#define WS_W21   49152    // f16 [256][64]  folded Wih2*Wc1
#define WS_WHH2  81920    // f16 [256][64]
#define WS_BX    114688   // f32 [256]
#define WS_B2    115712   // f32 [256]
#define WS_WH    116736   // f32 [64]       folded W_head*Wc2
#define WS_BH    116992   // f32 [1]

__device__ __forceinline__ float sig_pre(float v) {   // v already = -x*log2e
  return __builtin_amdgcn_rcpf(1.f + __builtin_amdgcn_exp2f(v));
}
__device__ __forceinline__ float tanh_pre(float v) {  // v already = x*2*log2e
  return 1.f - 2.f * __builtin_amdgcn_rcpf(1.f + __builtin_amdgcn_exp2f(v));
}
__device__ __forceinline__ float tanh_raw(float x) {
  return tanh_pre(x * S_TANH);
}

__global__ __launch_bounds__(256) void prep_kernel(
    const float* __restrict__ W_red, const float* __restrict__ b_red,
    const float* __restrict__ Wih1, const float* __restrict__ Whh1,
    const float* __restrict__ bih1, const float* __restrict__ bhh1,
    const float* __restrict__ Wc1,  const float* __restrict__ bc1,
    const float* __restrict__ Wih2, const float* __restrict__ Whh2,
    const float* __restrict__ bih2, const float* __restrict__ bhh2,
    const float* __restrict__ Wc2,  const float* __restrict__ bc2,
    const float* __restrict__ W_head, const float* __restrict__ b_head,
    unsigned char* __restrict__ ws)
{
  const int g = threadIdx.x;   // 0..255 gate row
  f16* WxH   = (f16*)(ws + WS_WX);
  f16* Whh1H = (f16*)(ws + WS_WHH1);
  f16* W21H  = (f16*)(ws + WS_W21);
  f16* Whh2H = (f16*)(ws + WS_WHH2);
  float* BX  = (float*)(ws + WS_BX);
  float* B2  = (float*)(ws + WS_B2);
  float* WHp = (float*)(ws + WS_WH);
  float* BHp = (float*)(ws + WS_BH);

  const float sc = ((g >> 6) == 2) ? S_TANH : S_SIG;  // gate g uses tanh

  // Wx row g = Wih1[g,:] @ W_red  (+ u/v denorm fold)
  float wxrow[CIN];
  for (int c = 0; c < CIN; ++c) {
    float s = 0.f;
    for (int r = 0; r < 24; ++r) s += Wih1[g*24 + r] * W_red[r*28 + c];
    wxrow[c] = s;
  }
  float bx = bih1[g] + bhh1[g];
  for (int r = 0; r < 24; ++r) bx += Wih1[g*24 + r] * b_red[r];
  bx += wxrow[11] * 0.02f + wxrow[12] * (-0.01f);   // MU_U, MU_V
  wxrow[11] *= 0.15f;                                // SD_U
  wxrow[12] *= 0.12f;                                // SD_V
  for (int c = 0; c < 32; ++c)
    WxH[g*32 + c] = (c < CIN) ? (f16)(wxrow[c] * sc) : (f16)0.f;
  BX[g] = bx * sc;

  for (int k = 0; k < 64; ++k) Whh1H[g*64 + k] = (f16)(Whh1[g*64 + k] * sc);

  // W21 row g = Wih2[g,:] @ Wc1
  float b2v = bih2[g] + bhh2[g];
  for (int m = 0; m < 64; ++m) b2v += Wih2[g*64 + m] * bc1[m];
  B2[g] = b2v * sc;
  for (int k = 0; k < 64; ++k) {
    float s = 0.f;
    for (int m = 0; m < 64; ++m) s += Wih2[g*64 + m] * Wc1[m*64 + k];
    W21H[g*64 + k]  = (f16)(s * sc);
    Whh2H[g*64 + k] = (f16)(Whh2[g*64 + k] * sc);
  }
  if (g < 64) {
    float s = 0.f;
    for (int m = 0; m < 64; ++m) s += W_head[m] * Wc2[m*64 + g];
    WHp[g] = s;
  }
  if (g == 0) {
    float s = b_head[0];
    for (int m = 0; m < 64; ++m) s += W_head[m] * bc2[m];
    BHp[0] = s;
  }
}

// Main: 64 pixels/block, 4 waves; wave w owns hidden cols [16w,16w+16) for all
// 64 pixels; ALL weight B-fragments register-resident (incl wx); h1/h2
// double-buffered LDS; x double-buffered LDS with register prefetch pipeline.
// waves_per_eu(2,2): pin 256-reg budget (unified VGPR+AGPR) -> zero spill.
__global__ __launch_bounds__(256)
__attribute__((amdgpu_waves_per_eu(2, 2)))
void convlstm_main(
    const float* __restrict__ x, const unsigned char* __restrict__ ws,
    float* __restrict__ out)
{
  __shared__ __align__(16) f16 xs[2][64 * 40];       // [pixel][ch], stride 40
  __shared__ __align__(16) f16 h1buf[2][64 * 72];    // [pixel][hid], stride 72
  __shared__ __align__(16) f16 h2buf[2][64 * 72];
  __shared__ float outpart[64][4];

  const int tid  = threadIdx.x;
  const int lane = tid & 63;
  const int wv   = tid >> 6;     // wave 0..3
  const int cl   = lane & 15;    // MFMA "lane&15"
  const int qd   = lane >> 4;    // MFMA quad

  const f16* WxG   = (const f16*)(ws + WS_WX);
  const f16* Whh1G = (const f16*)(ws + WS_WHH1);
  const f16* W21G  = (const f16*)(ws + WS_W21);
  const f16* Whh2G = (const f16*)(ws + WS_WHH2);
  const float* BX  = (const float*)(ws + WS_BX);
  const float* B2  = (const float*)(ws + WS_B2);

  // ---- per-wave weight fragments in registers (B layout: [n][k]) ----
  f16x8 wxf[4], whh1f[4][2], w21f[4][2], whh2f[4][2];
  float bxr[4], b2r[4];
#pragma unroll
  for (int P = 0; P < 4; ++P) {                      // i,f,g,o
    const int gr = 64*P + 16*wv + cl;
    wxf[P] = *(const f16x8*)(WxG + gr*32 + qd*8);
#pragma unroll
    for (int s = 0; s < 2; ++s) {
      whh1f[P][s] = *(const f16x8*)(Whh1G + gr*64 + s*32 + qd*8);
      w21f[P][s]  = *(const f16x8*)(W21G  + gr*64 + s*32 + qd*8);
      whh2f[P][s] = *(const f16x8*)(Whh2G + gr*64 + s*32 + qd*8);
    }
    bxr[P] = BX[gr];
    b2r[P] = B2[gr];
  }
  const float whc   = ((const float*)(ws + WS_WH))[16*wv + cl];
  const float bhead = *((const float*)(ws + WS_BH));

  // zero t=0 h buffers
  {
    unsigned* z1 = (unsigned*)&h1buf[0][0];
    unsigned* z2 = (unsigned*)&h2buf[0][0];
#pragma unroll
    for (int i = tid; i < 2304; i += 256) { z1[i] = 0u; z2[i] = 0u; }
  }

  const int gpix = blockIdx.x * 64;
  const float* xb = x + (size_t)(gpix >> 14) * (TT * CIN * HW) + (gpix & (HW - 1));

  // stage x_0
#pragma unroll
  for (int e = tid; e < 2048; e += 256) {
    const int ch = e >> 6, p = e & 63;
    xs[0][p*40 + ch] = (ch < CIN) ? (f16)xb[ch*HW + p] : (f16)0.f;
  }
  __syncthreads();

  float c1s[4][4], c2s[4][4];
#pragma unroll
  for (int a = 0; a < 4; ++a)
#pragma unroll
    for (int b = 0; b < 4; ++b) { c1s[a][b] = 0.f; c2s[a][b] = 0.f; }

#pragma unroll 1
  for (int t = 0; t < TT; ++t) {
    // ---- prefetch x_{t+1} into registers (latency hidden under compute) ----
    float xr[8];
    if (t + 1 < TT) {
      const float* xt = xb + (size_t)(t + 1) * (CIN * HW);
#pragma unroll
      for (int i = 0; i < 8; ++i) {
        const int e = tid + i*256;
        const int ch = e >> 6, p = e & 63;
        xr[i] = (ch < CIN) ? xt[ch*HW + p] : 0.f;
      }
    }

    const f16* xsr = xs[t & 1];
    const f16* h1r = h1buf[t & 1];
    const f16* h2r = h2buf[t & 1];
    f16* h1w = h1buf[(t + 1) & 1];
    f16* h2w = h2buf[(t + 1) & 1];

    // ---- layer 1: gates = Wx*x + Whh1*h1 + b, in two pixel-block halves ----
#pragma unroll
    for (int hb = 0; hb < 2; ++hb) {
      f32x4 acc[2][4];
#pragma unroll
      for (int m = 0; m < 2; ++m) {
        const int p = 16*(hb*2 + m) + cl;
        const f16x8 ax  = *(const f16x8*)(xsr + p*40 + qd*8);
        const f16x8 ah0 = *(const f16x8*)(h1r + p*72 + qd*8);
        const f16x8 ah1 = *(const f16x8*)(h1r + p*72 + 32 + qd*8);
#pragma unroll
        for (int P = 0; P < 4; ++P) {
          f32x4 a = { bxr[P], bxr[P], bxr[P], bxr[P] };
          a = __builtin_amdgcn_mfma_f32_16x16x32_f16(ax,  wxf[P],      a, 0, 0, 0);
          a = __builtin_amdgcn_mfma_f32_16x16x32_f16(ah0, whh1f[P][0], a, 0, 0, 0);
          a = __builtin_amdgcn_mfma_f32_16x16x32_f16(ah1, whh1f[P][1], a, 0, 0, 0);
          acc[m][P] = a;
        }
      }
#pragma unroll
      for (int m = 0; m < 2; ++m) {
        const int mb = hb*2 + m;
#pragma unroll
        for (int r = 0; r < 4; ++r) {
          const float ig = sig_pre(acc[m][0][r]);
          const float fg = sig_pre(acc[m][1][r]);
          const float gg = tanh_pre(acc[m][2][r]);
          const float og = sig_pre(acc[m][3][r]);
          const float cn = fg * c1s[mb][r] + ig * gg;
          c1s[mb][r] = cn;
          const float hn = og * tanh_raw(cn);
          h1w[(16*mb + 4*qd + r)*72 + 16*wv + cl] = (f16)hn;
        }
      }
    }
    __syncthreads();

    // ---- layer 2: gates = W21*h1_new + Whh2*h2 + b, two halves ----
#pragma unroll
    for (int hb = 0; hb < 2; ++hb) {
      f32x4 acc[2][4];
#pragma unroll
      for (int m = 0; m < 2; ++m) {
        const int p = 16*(hb*2 + m) + cl;
        const f16x8 an0 = *(const f16x8*)(h1w + p*72 + qd*8);
        const f16x8 an1 = *(const f16x8*)(h1w + p*72 + 32 + qd*8);
        const f16x8 a20 = *(const f16x8*)(h2r + p*72 + qd*8);
        const f16x8 a21 = *(const f16x8*)(h2r + p*72 + 32 + qd*8);
#pragma unroll
        for (int P = 0; P < 4; ++P) {
          f32x4 a = { b2r[P], b2r[P], b2r[P], b2r[P] };
          a = __builtin_amdgcn_mfma_f32_16x16x32_f16(an0, w21f[P][0],  a, 0, 0, 0);
          a = __builtin_amdgcn_mfma_f32_16x16x32_f16(an1, w21f[P][1],  a, 0, 0, 0);
          a = __builtin_amdgcn_mfma_f32_16x16x32_f16(a20, whh2f[P][0], a, 0, 0, 0);
          a = __builtin_amdgcn_mfma_f32_16x16x32_f16(a21, whh2f[P][1], a, 0, 0, 0);
          acc[m][P] = a;
        }
      }
#pragma unroll
      for (int m = 0; m < 2; ++m) {
        const int mb = hb*2 + m;
#pragma unroll
        for (int r = 0; r < 4; ++r) {
          const float ig = sig_pre(acc[m][0][r]);
          const float fg = sig_pre(acc[m][1][r]);
          const float gg = tanh_pre(acc[m][2][r]);
          const float og = sig_pre(acc[m][3][r]);
          const float cn = fg * c2s[mb][r] + ig * gg;
          c2s[mb][r] = cn;
          const float hn = og * tanh_raw(cn);
          h2w[(16*mb + 4*qd + r)*72 + 16*wv + cl] = (f16)hn;
          if (t == TT - 1) {
            float pa = hn * whc;
            pa += __shfl_xor(pa, 1, 64);
            pa += __shfl_xor(pa, 2, 64);
            pa += __shfl_xor(pa, 4, 64);
            pa += __shfl_xor(pa, 8, 64);
            if (cl == 0) outpart[16*mb + 4*qd + r][wv] = pa;
          }
        }
      }
    }

    // ---- store prefetched x_{t+1} into the other xs buffer ----
    if (t + 1 < TT) {
      f16* xsw = xs[(t + 1) & 1];
#pragma unroll
      for (int i = 0; i < 8; ++i) {
        const int e = tid + i*256;
        const int ch = e >> 6, p = e & 63;
        xsw[p*40 + ch] = (f16)xr[i];
      }
    }
    __syncthreads();
  }

  if (tid < 64) {
    out[gpix + tid] = outpart[tid][0] + outpart[tid][1] +
                      outpart[tid][2] + outpart[tid][3] + bhead;
  }
}

extern "C" void kernel_launch(void* const* d_in, const int* in_sizes, int n_in,
                              void* d_out, int out_size, void* d_ws, size_t ws_size,
                              hipStream_t stream) {
  const float* x      = (const float*)d_in[0];
  const float* W_red  = (const float*)d_in[1];
  const float* b_red  = (const float*)d_in[2];
  const float* Wih1   = (const float*)d_in[3];
  const float* Whh1   = (const float*)d_in[4];
  const float* bih1   = (const float*)d_in[5];
  const float* bhh1   = (const float*)d_in[6];
  const float* Wc1    = (const float*)d_in[7];
  const float* bc1    = (const float*)d_in[8];
  const float* Wih2   = (const float*)d_in[9];
  const float* Whh2   = (const float*)d_in[10];
  const float* bih2   = (const float*)d_in[11];
  const float* bhh2   = (const float*)d_in[12];
  const float* Wc2    = (const float*)d_in[13];
  const float* bc2    = (const float*)d_in[14];
  const float* W_head = (const float*)d_in[15];
  const float* b_head = (const float*)d_in[16];

  prep_kernel<<<1, 256, 0, stream>>>(W_red, b_red, Wih1, Whh1, bih1, bhh1,
                                     Wc1, bc1, Wih2, Whh2, bih2, bhh2,
                                     Wc2, bc2, W_head, b_head,
                                     (unsigned char*)d_ws);
  convlstm_main<<<2048, 256, 0, stream>>>(x, (const unsigned char*)d_ws,
                                          (float*)d_out);
}

// Round 3
// 570.907 us; speedup vs baseline: 1.3108x; 1.0861x over previous
//
#include <hip/hip_runtime.h>

typedef _Float16 f16;
typedef _Float16 f16x8 __attribute__((ext_vector_type(8)));
typedef float f32x4 __attribute__((ext_vector_type(4)));

#define CIN 28
#define TT 8
#define HW 16384

// gate pre-scales folded into weights: sigmoid(x)=rcp(1+exp2(-x*log2e)),
// tanh(x)=1-2*rcp(1+exp2(x*2*log2e))
#define S_SIG  (-1.44269504088896341f)
#define S_TANH ( 2.88539008177792681f)

// workspace layout (bytes)
#define WS_WX    0        // f16 [256][32]  folded Wih1*W_red (+denorm scales, gate scale)
#define WS_WHH1  16384    // f16 [256][64]
#define WS_W21   49152    // f16 [256][64]  folded Wih2*Wc1
#define WS_WHH2  81920    // f16 [256][64]
#define WS_BX    114688   // f32 [256]
#define WS_B2    115712   // f32 [256]
#define WS_WH    116736   // f32 [64]       folded W_head*Wc2
#define WS_BH    116992   // f32 [1]

__device__ __forceinline__ float sig_pre(float v) {   // v already = -x*log2e
  return __builtin_amdgcn_rcpf(1.f + __builtin_amdgcn_exp2f(v));
}
__device__ __forceinline__ float tanh_pre(float v) {  // v already = x*2*log2e
  return 1.f - 2.f * __builtin_amdgcn_rcpf(1.f + __builtin_amdgcn_exp2f(v));
}
__device__ __forceinline__ float tanh_raw(float x) {
  return tanh_pre(x * S_TANH);
}

// MFMA with B operand pinned in AGPRs (frees arch VGPRs; gfx950 unified file).
// First-of-chain variant has s_nop for the VALU-write -> MFMA-read-C hazard
// (inline asm is opaque to the hazard recognizer). The LAST mfma of every
// accumulation chain is the __builtin (VGPR B) so the compiler handles the
// MFMA -> VALU-read-of-acc hazard itself.
__device__ __forceinline__ void mfma_agf(f32x4& c, f16x8 a, f16x8 b) {
  asm("s_nop 1\n\tv_mfma_f32_16x16x32_f16 %0, %1, %2, %0"
      : "+v"(c) : "v"(a), "a"(b));
}
__device__ __forceinline__ void mfma_ag(f32x4& c, f16x8 a, f16x8 b) {
  asm("v_mfma_f32_16x16x32_f16 %0, %1, %2, %0"
      : "+v"(c) : "v"(a), "a"(b));
}
// AGPR-resident scalar state (c2) helpers
__device__ __forceinline__ float ag_get(float a) {
  float v; asm("v_accvgpr_read_b32 %0, %1" : "=v"(v) : "a"(a)); return v;
}
__device__ __forceinline__ float ag_put(float v) {
  float a; asm("v_accvgpr_write_b32 %0, %1" : "=a"(a) : "v"(v)); return a;
}

__global__ __launch_bounds__(256) void prep_kernel(
    const float* __restrict__ W_red, const float* __restrict__ b_red,
    const float* __restrict__ Wih1, const float* __restrict__ Whh1,
    const float* __restrict__ bih1, const float* __restrict__ bhh1,
    const float* __restrict__ Wc1,  const float* __restrict__ bc1,
    const float* __restrict__ Wih2, const float* __restrict__ Whh2,
    const float* __restrict__ bih2, const float* __restrict__ bhh2,
    const float* __restrict__ Wc2,  const float* __restrict__ bc2,
    const float* __restrict__ W_head, const float* __restrict__ b_head,
    unsigned char* __restrict__ ws)
{
  const int g = threadIdx.x;   // 0..255 gate row
  f16* WxH   = (f16*)(ws + WS_WX);
  f16* Whh1H = (f16*)(ws + WS_WHH1);
  f16* W21H  = (f16*)(ws + WS_W21);
  f16* Whh2H = (f16*)(ws + WS_WHH2);
  float* BX  = (float*)(ws + WS_BX);
  float* B2  = (float*)(ws + WS_B2);
  float* WHp = (float*)(ws + WS_WH);
  float* BHp = (float*)(ws + WS_BH);

  const float sc = ((g >> 6) == 2) ? S_TANH : S_SIG;  // gate g uses tanh

  // Wx row g = Wih1[g,:] @ W_red  (+ u/v denorm fold)
  float wxrow[CIN];
  for (int c = 0; c < CIN; ++c) {
    float s = 0.f;
    for (int r = 0; r < 24; ++r) s += Wih1[g*24 + r] * W_red[r*28 + c];
    wxrow[c] = s;
  }
  float bx = bih1[g] + bhh1[g];
  for (int r = 0; r < 24; ++r) bx += Wih1[g*24 + r] * b_red[r];
  bx += wxrow[11] * 0.02f + wxrow[12] * (-0.01f);   // MU_U, MU_V
  wxrow[11] *= 0.15f;                                // SD_U
  wxrow[12] *= 0.12f;                                // SD_V
  for (int c = 0; c < 32; ++c)
    WxH[g*32 + c] = (c < CIN) ? (f16)(wxrow[c] * sc) : (f16)0.f;
  BX[g] = bx * sc;

  for (int k = 0; k < 64; ++k) Whh1H[g*64 + k] = (f16)(Whh1[g*64 + k] * sc);

  // W21 row g = Wih2[g,:] @ Wc1
  float b2v = bih2[g] + bhh2[g];
  for (int m = 0; m < 64; ++m) b2v += Wih2[g*64 + m] * bc1[m];
  B2[g] = b2v * sc;
  for (int k = 0; k < 64; ++k) {
    float s = 0.f;
    for (int m = 0; m < 64; ++m) s += Wih2[g*64 + m] * Wc1[m*64 + k];
    W21H[g*64 + k]  = (f16)(s * sc);
    Whh2H[g*64 + k] = (f16)(Whh2[g*64 + k] * sc);
  }
  if (g < 64) {
    float s = 0.f;
    for (int m = 0; m < 64; ++m) s += W_head[m] * Wc2[m*64 + g];
    WHp[g] = s;
  }
  if (g == 0) {
    float s = b_head[0];
    for (int m = 0; m < 64; ++m) s += W_head[m] * bc2[m];
    BHp[0] = s;
  }
}

// 64 pixels/block, 4 waves; wave w owns hidden cols [16w,16w+16) x all 4
// gates for all 64 pixels. Recurrent weight B-frags: whh1[0..1], w21[0..1],
// whh2[0] in AGPRs (inline-asm MFMA), wx + whh2[1] in VGPRs (builtin MFMA,
// last of each chain). c2 state in AGPRs. Arch-VGPR demand ~115 < 128 cap.
__global__ __launch_bounds__(256)
__attribute__((amdgpu_waves_per_eu(2, 2)))
void convlstm_main(
    const float* __restrict__ x, const unsigned char* __restrict__ ws,
    float* __restrict__ out)
{
  __shared__ __align__(16) f16 xs[2][64 * 40];       // [pixel][ch], stride 40
  __shared__ __align__(16) f16 h1buf[2][64 * 72];    // [pixel][hid], stride 72
  __shared__ __align__(16) f16 h2buf[2][64 * 72];

  const int tid  = threadIdx.x;
  const int lane = tid & 63;
  const int wv   = tid >> 6;     // wave 0..3
  const int cl   = lane & 15;    // MFMA "lane&15"
  const int qd   = lane >> 4;    // MFMA quad

  const f16* WxG   = (const f16*)(ws + WS_WX);
  const f16* Whh1G = (const f16*)(ws + WS_WHH1);
  const f16* W21G  = (const f16*)(ws + WS_W21);
  const f16* Whh2G = (const f16*)(ws + WS_WHH2);
  const float* BX  = (const float*)(ws + WS_BX);
  const float* B2  = (const float*)(ws + WS_B2);

  // ---- weight fragments (B layout: [n=gate-slice][k]) ----
  f16x8 wxf[4], whh2v[4];                 // VGPR-resident (chain-enders)
  f16x8 whh1a[4][2], w21a[4][2], whh2a[4]; // AGPR-resident (asm-only uses)
  float bxr[4], b2r[4];
#pragma unroll
  for (int P = 0; P < 4; ++P) {                      // i,f,g,o
    const int gr = 64*P + 16*wv + cl;
    wxf[P] = *(const f16x8*)(WxG + gr*32 + qd*8);
    whh1a[P][0] = *(const f16x8*)(Whh1G + gr*64 + qd*8);
    whh1a[P][1] = *(const f16x8*)(Whh1G + gr*64 + 32 + qd*8);
    w21a[P][0]  = *(const f16x8*)(W21G  + gr*64 + qd*8);
    w21a[P][1]  = *(const f16x8*)(W21G  + gr*64 + 32 + qd*8);
    whh2a[P]    = *(const f16x8*)(Whh2G + gr*64 + qd*8);
    whh2v[P]    = *(const f16x8*)(Whh2G + gr*64 + 32 + qd*8);
    bxr[P] = BX[gr];
    b2r[P] = B2[gr];
  }

  // zero t=0 h buffers
  {
    unsigned* z1 = (unsigned*)&h1buf[0][0];
    unsigned* z2 = (unsigned*)&h2buf[0][0];
#pragma unroll
    for (int i = tid; i < 2304; i += 256) { z1[i] = 0u; z2[i] = 0u; }
  }

  const int gpix = blockIdx.x * 64;
  const float* xb = x + (size_t)(gpix >> 14) * (TT * CIN * HW) + (gpix & (HW - 1));

  // stage x_0
#pragma unroll
  for (int e = tid; e < 2048; e += 256) {
    const int ch = e >> 6, p = e & 63;
    xs[0][p*40 + ch] = (ch < CIN) ? (f16)xb[ch*HW + p] : (f16)0.f;
  }
  __syncthreads();

  float c1s[4][4];   // VGPR
  float c2s[4][4];   // AGPR-homed (ag_get/ag_put only)
#pragma unroll
  for (int a = 0; a < 4; ++a)
#pragma unroll
    for (int b = 0; b < 4; ++b) { c1s[a][b] = 0.f; c2s[a][b] = ag_put(0.f); }

#pragma unroll 1
  for (int t = 0; t < TT; ++t) {
    // ---- prefetch x_{t+1} into registers (consumed at loop bottom) ----
    float xr[8];
    if (t + 1 < TT) {
      const float* xt = xb + (size_t)(t + 1) * (CIN * HW);
#pragma unroll
      for (int i = 0; i < 8; ++i) {
        const int e = tid + i*256;
        const int ch = e >> 6, p = e & 63;
        xr[i] = (ch < CIN) ? xt[ch*HW + p] : 0.f;
      }
    }

    const f16* xsr = xs[t & 1];
    const f16* h1r = h1buf[t & 1];
    const f16* h2r = h2buf[t & 1];
    f16* h1w = h1buf[(t + 1) & 1];
    f16* h2w = h2buf[(t + 1) & 1];

    // ---- layer 1: gates = Whh1*h1 + Wx*x + b ----
#pragma unroll
    for (int mb = 0; mb < 4; ++mb) {
      const int p = 16*mb + cl;
      const f16x8 ax  = *(const f16x8*)(xsr + p*40 + qd*8);
      const f16x8 ah0 = *(const f16x8*)(h1r + p*72 + qd*8);
      const f16x8 ah1 = *(const f16x8*)(h1r + p*72 + 32 + qd*8);
      f32x4 acc[4];
#pragma unroll
      for (int P = 0; P < 4; ++P) {
        acc[P] = (f32x4){ bxr[P], bxr[P], bxr[P], bxr[P] };
        mfma_agf(acc[P], ah0, whh1a[P][0]);
        mfma_ag (acc[P], ah1, whh1a[P][1]);
        acc[P] = __builtin_amdgcn_mfma_f32_16x16x32_f16(ax, wxf[P], acc[P], 0, 0, 0);
      }
#pragma unroll
      for (int r = 0; r < 4; ++r) {
        const float ig = sig_pre(acc[0][r]);
        const float fg = sig_pre(acc[1][r]);
        const float gg = tanh_pre(acc[2][r]);
        const float og = sig_pre(acc[3][r]);
        const float cn = fg * c1s[mb][r] + ig * gg;
        c1s[mb][r] = cn;
        const float hn = og * tanh_raw(cn);
        h1w[(16*mb + 4*qd + r)*72 + 16*wv + cl] = (f16)hn;
      }
    }
    __syncthreads();

    // ---- layer 2: gates = W21*h1_new + Whh2*h2 + b ----
#pragma unroll
    for (int mb = 0; mb < 4; ++mb) {
      const int p = 16*mb + cl;
      const f16x8 an0 = *(const f16x8*)(h1w + p*72 + qd*8);
      const f16x8 an1 = *(const f16x8*)(h1w + p*72 + 32 + qd*8);
      const f16x8 a20 = *(const f16x8*)(h2r + p*72 + qd*8);
      const f16x8 a21 = *(const f16x8*)(h2r + p*72 + 32 + qd*8);
      f32x4 acc[4];
#pragma unroll
      for (int P = 0; P < 4; ++P) {
        acc[P] = (f32x4){ b2r[P], b2r[P], b2r[P], b2r[P] };
        mfma_agf(acc[P], an0, w21a[P][0]);
        mfma_ag (acc[P], an1, w21a[P][1]);
        mfma_ag (acc[P], a20, whh2a[P]);
        acc[P] = __builtin_amdgcn_mfma_f32_16x16x32_f16(a21, whh2v[P], acc[P], 0, 0, 0);
      }
#pragma unroll
      for (int r = 0; r < 4; ++r) {
        const float ig = sig_pre(acc[0][r]);
        const float fg = sig_pre(acc[1][r]);
        const float gg = tanh_pre(acc[2][r]);
        const float og = sig_pre(acc[3][r]);
        const float co = ag_get(c2s[mb][r]);
        const float cn = fg * co + ig * gg;
        c2s[mb][r] = ag_put(cn);
        const float hn = og * tanh_raw(cn);
        h2w[(16*mb + 4*qd + r)*72 + 16*wv + cl] = (f16)hn;
      }
    }

    // ---- store prefetched x_{t+1} ----
    if (t + 1 < TT) {
      f16* xsw = xs[(t + 1) & 1];
#pragma unroll
      for (int i = 0; i < 8; ++i) {
        const int e = tid + i*256;
        const int ch = e >> 6, p = e & 63;
        xsw[p*40 + ch] = (f16)xr[i];
      }
    }
    __syncthreads();
  }

  // ---- head epilogue: out[p] = bhead + sum_k h2[p][k] * wh[k] ----
  if (tid < 64) {
    const float* wh = (const float*)(ws + WS_WH);
    const f16* row = &h2buf[0][tid * 72];   // final h2 lives in buffer 0
    float s = *((const float*)(ws + WS_BH));
#pragma unroll
    for (int k = 0; k < 64; ++k) s += (float)row[k] * wh[k];
    out[gpix + tid] = s;
  }
}

extern "C" void kernel_launch(void* const* d_in, const int* in_sizes, int n_in,
                              void* d_out, int out_size, void* d_ws, size_t ws_size,
                              hipStream_t stream) {
  const float* x      = (const float*)d_in[0];
  const float* W_red  = (const float*)d_in[1];
  const float* b_red  = (const float*)d_in[2];
  const float* Wih1   = (const float*)d_in[3];
  const float* Whh1   = (const float*)d_in[4];
  const float* bih1   = (const float*)d_in[5];
  const float* bhh1   = (const float*)d_in[6];
  const float* Wc1    = (const float*)d_in[7];
  const float* bc1    = (const float*)d_in[8];
  const float* Wih2   = (const float*)d_in[9];
  const float* Whh2   = (const float*)d_in[10];
  const float* bih2   = (const float*)d_in[11];
  const float* bhh2   = (const float*)d_in[12];
  const float* Wc2    = (const float*)d_in[13];
  const float* bc2    = (const float*)d_in[14];
  const float* W_head = (const float*)d_in[15];
  const float* b_head = (const float*)d_in[16];

  prep_kernel<<<1, 256, 0, stream>>>(W_red, b_red, Wih1, Whh1, bih1, bhh1,
                                     Wc1, bc1, Wih2, Whh2, bih2, bhh2,
                                     Wc2, bc2, W_head, b_head,
                                     (unsigned char*)d_ws);
  convlstm_main<<<2048, 256, 0, stream>>>(x, (const unsigned char*)d_ws,
                                          (float*)d_out);
}

// Round 4
// 391.008 us; speedup vs baseline: 1.9139x; 1.4601x over previous
//
#include <hip/hip_runtime.h>

typedef _Float16 f16;
typedef _Float16 f16x8 __attribute__((ext_vector_type(8)));
typedef float f32x4 __attribute__((ext_vector_type(4)));

#define CIN 28
#define TT 8
#define HW 16384

// gate pre-scales folded into weights: sigmoid(x)=rcp(1+exp2(-x*log2e)),
// tanh(x)=1-2*rcp(1+exp2(x*2*log2e))
#define S_SIG  (-1.44269504088896341f)
#define S_TANH ( 2.88539008177792681f)

// workspace layout (bytes)
#define WS_WX    0        // f16 [256][32]  folded Wih1*W_red (+denorm scales, gate scale)
#define WS_WHH1  16384    // f16 [256][64]
#define WS_W21   49152    // f16 [256][64]  folded Wih2*Wc1
#define WS_WHH2  81920    // f16 [256][64]
#define WS_BX    114688   // f32 [256]
#define WS_B2    115712   // f32 [256]
#define WS_WH    116736   // f32 [64]       folded W_head*Wc2
#define WS_BH    116992   // f32 [1]

__device__ __forceinline__ float sig_pre(float v) {   // v already = -x*log2e
  return __builtin_amdgcn_rcpf(1.f + __builtin_amdgcn_exp2f(v));
}
__device__ __forceinline__ float tanh_pre(float v) {  // v already = x*2*log2e
  return 1.f - 2.f * __builtin_amdgcn_rcpf(1.f + __builtin_amdgcn_exp2f(v));
}
__device__ __forceinline__ float tanh_raw(float x) {
  return tanh_pre(x * S_TANH);
}

// MFMA with B operand pinned in AGPRs (frees arch VGPRs; gfx950 unified file).
// First-of-chain variant has s_nop for the VALU-write -> MFMA-read-C hazard
// (inline asm is opaque to the hazard recognizer). The LAST mfma of every
// accumulation chain is the __builtin (VGPR B) so the compiler handles the
// MFMA -> VALU-read-of-acc hazard itself.
__device__ __forceinline__ void mfma_agf(f32x4& c, f16x8 a, f16x8 b) {
  asm("s_nop 1\n\tv_mfma_f32_16x16x32_f16 %0, %1, %2, %0"
      : "+v"(c) : "v"(a), "a"(b));
}
__device__ __forceinline__ void mfma_ag(f32x4& c, f16x8 a, f16x8 b) {
  asm("v_mfma_f32_16x16x32_f16 %0, %1, %2, %0"
      : "+v"(c) : "v"(a), "a"(b));
}
// AGPR-resident scalar state (c2) helpers
__device__ __forceinline__ float ag_get(float a) {
  float v; asm("v_accvgpr_read_b32 %0, %1" : "=v"(v) : "a"(a)); return v;
}
__device__ __forceinline__ float ag_put(float v) {
  float a; asm("v_accvgpr_write_b32 %0, %1" : "=a"(a) : "v"(v)); return a;
}

// Parallel prep: 256 blocks (one per gate row g) x 64 threads (one per k).
// Round-3 post-mortem: the old 1-block prep was ~290 us (serial 64x64 dot
// chains on one CU) — bigger than the main kernel.
__global__ __launch_bounds__(64) void prep_kernel(
    const float* __restrict__ W_red, const float* __restrict__ b_red,
    const float* __restrict__ Wih1, const float* __restrict__ Whh1,
    const float* __restrict__ bih1, const float* __restrict__ bhh1,
    const float* __restrict__ Wc1,  const float* __restrict__ bc1,
    const float* __restrict__ Wih2, const float* __restrict__ Whh2,
    const float* __restrict__ bih2, const float* __restrict__ bhh2,
    const float* __restrict__ Wc2,  const float* __restrict__ bc2,
    const float* __restrict__ W_head, const float* __restrict__ b_head,
    unsigned char* __restrict__ ws)
{
  const int g = blockIdx.x;    // 0..255 gate row
  const int k = threadIdx.x;   // 0..63
  f16* WxH   = (f16*)(ws + WS_WX);
  f16* Whh1H = (f16*)(ws + WS_WHH1);
  f16* W21H  = (f16*)(ws + WS_W21);
  f16* Whh2H = (f16*)(ws + WS_WHH2);
  float* BX  = (float*)(ws + WS_BX);
  float* B2  = (float*)(ws + WS_B2);
  float* WHp = (float*)(ws + WS_WH);
  float* BHp = (float*)(ws + WS_BH);

  const float sc = ((g >> 6) == 2) ? S_TANH : S_SIG;  // gate g uses tanh

  // Wx[g][k] = Wih1[g,:] @ W_red[:,k]  (k < CIN), + u/v denorm fold
  float wxv = 0.f;
  if (k < CIN) {
    float s = 0.f;
    for (int r = 0; r < 24; ++r) s += Wih1[g*24 + r] * W_red[r*28 + k];
    wxv = s;
  }
  const float wx11 = __shfl(wxv, 11, 64);   // pre-scale values for bias fold
  const float wx12 = __shfl(wxv, 12, 64);
  if (k == 11) wxv *= 0.15f;                // SD_U
  if (k == 12) wxv *= 0.12f;                // SD_V
  if (k < 32) WxH[g*32 + k] = (f16)(wxv * sc);

  Whh1H[g*64 + k] = (f16)(Whh1[g*64 + k] * sc);
  Whh2H[g*64 + k] = (f16)(Whh2[g*64 + k] * sc);

  // W21[g][k] = Wih2[g,:] @ Wc1[:,k]   (Wih2 row broadcast, Wc1 coalesced)
  {
    float s = 0.f;
    for (int m = 0; m < 64; ++m) s += Wih2[g*64 + m] * Wc1[m*64 + k];
    W21H[g*64 + k] = (f16)(s * sc);
  }

  if (k == 0) {
    float bx = bih1[g] + bhh1[g];
    for (int r = 0; r < 24; ++r) bx += Wih1[g*24 + r] * b_red[r];
    bx += wx11 * 0.02f + wx12 * (-0.01f);   // MU_U, MU_V
    BX[g] = bx * sc;
    float b2v = bih2[g] + bhh2[g];
    for (int m = 0; m < 64; ++m) b2v += Wih2[g*64 + m] * bc1[m];
    B2[g] = b2v * sc;
  }
  if (g == 0) {
    float s = 0.f;
    for (int m = 0; m < 64; ++m) s += W_head[m] * Wc2[m*64 + k];
    WHp[k] = s;
    if (k == 0) {
      float s2 = b_head[0];
      for (int m = 0; m < 64; ++m) s2 += W_head[m] * bc2[m];
      BHp[0] = s2;
    }
  }
}

// 64 pixels/block, 4 waves; wave w owns hidden cols [16w,16w+16) x all 4
// gates for all 64 pixels. Recurrent weight B-frags: whh1[0..1], w21[0..1],
// whh2[0] in AGPRs (inline-asm MFMA), wx + whh2[1] in VGPRs (builtin MFMA,
// last of each chain). c2 state in AGPRs. Arch-VGPR demand ~115 < 128 cap.
// x staging: thread owns (pixel=lane, 8 consecutive channels) -> one
// ds_write_b128 per step instead of 8 ds_write_b16.
__global__ __launch_bounds__(256)
__attribute__((amdgpu_waves_per_eu(2, 2)))
void convlstm_main(
    const float* __restrict__ x, const unsigned char* __restrict__ ws,
    float* __restrict__ out)
{
  __shared__ __align__(16) f16 xs[2][64 * 40];       // [pixel][ch], stride 40
  __shared__ __align__(16) f16 h1buf[2][64 * 72];    // [pixel][hid], stride 72
  __shared__ __align__(16) f16 h2buf[2][64 * 72];

  const int tid  = threadIdx.x;
  const int lane = tid & 63;
  const int wv   = tid >> 6;     // wave 0..3
  const int cl   = lane & 15;    // MFMA "lane&15"
  const int qd   = lane >> 4;    // MFMA quad

  const f16* WxG   = (const f16*)(ws + WS_WX);
  const f16* Whh1G = (const f16*)(ws + WS_WHH1);
  const f16* W21G  = (const f16*)(ws + WS_W21);
  const f16* Whh2G = (const f16*)(ws + WS_WHH2);
  const float* BX  = (const float*)(ws + WS_BX);
  const float* B2  = (const float*)(ws + WS_B2);

  // ---- weight fragments (B layout: [n=gate-slice][k]) ----
  f16x8 wxf[4], whh2v[4];                 // VGPR-resident (chain-enders)
  f16x8 whh1a[4][2], w21a[4][2], whh2a[4]; // AGPR-resident (asm-only uses)
  float bxr[4], b2r[4];
#pragma unroll
  for (int P = 0; P < 4; ++P) {                      // i,f,g,o
    const int gr = 64*P + 16*wv + cl;
    wxf[P] = *(const f16x8*)(WxG + gr*32 + qd*8);
    whh1a[P][0] = *(const f16x8*)(Whh1G + gr*64 + qd*8);
    whh1a[P][1] = *(const f16x8*)(Whh1G + gr*64 + 32 + qd*8);
    w21a[P][0]  = *(const f16x8*)(W21G  + gr*64 + qd*8);
    w21a[P][1]  = *(const f16x8*)(W21G  + gr*64 + 32 + qd*8);
    whh2a[P]    = *(const f16x8*)(Whh2G + gr*64 + qd*8);
    whh2v[P]    = *(const f16x8*)(Whh2G + gr*64 + 32 + qd*8);
    bxr[P] = BX[gr];
    b2r[P] = B2[gr];
  }

  // zero t=0 h buffers
  {
    unsigned* z1 = (unsigned*)&h1buf[0][0];
    unsigned* z2 = (unsigned*)&h2buf[0][0];
#pragma unroll
    for (int i = tid; i < 2304; i += 256) { z1[i] = 0u; z2[i] = 0u; }
  }

  const int gpix = blockIdx.x * 64;
  const float* xb = x + (size_t)(gpix >> 14) * (TT * CIN * HW) + (gpix & (HW - 1));

  const int sp = lane;        // staging pixel
  const int cb = wv * 8;      // staging channel base: 0,8,16,24

  // stage x_0: one f16x8 (ds_write_b128) per thread
  {
    f16x8 v;
#pragma unroll
    for (int j = 0; j < 8; ++j) {
      const int ch = cb + j;
      v[j] = (ch < CIN) ? (f16)xb[ch*HW + sp] : (f16)0.f;
    }
    *(f16x8*)(&xs[0][sp*40 + cb]) = v;
  }
  __syncthreads();

  float c1s[4][4];   // VGPR
  float c2s[4][4];   // AGPR-homed (ag_get/ag_put only)
#pragma unroll
  for (int a = 0; a < 4; ++a)
#pragma unroll
    for (int b = 0; b < 4; ++b) { c1s[a][b] = 0.f; c2s[a][b] = ag_put(0.f); }

#pragma unroll 1
  for (int t = 0; t < TT; ++t) {
    // ---- prefetch x_{t+1} into registers (consumed at loop bottom) ----
    float xr[8];
    if (t + 1 < TT) {
      const float* xt = xb + (size_t)(t + 1) * (CIN * HW);
#pragma unroll
      for (int j = 0; j < 8; ++j) {
        const int ch = cb + j;
        xr[j] = (ch < CIN) ? xt[ch*HW + sp] : 0.f;
      }
    }

    const f16* xsr = xs[t & 1];
    const f16* h1r = h1buf[t & 1];
    const f16* h2r = h2buf[t & 1];
    f16* h1w = h1buf[(t + 1) & 1];
    f16* h2w = h2buf[(t + 1) & 1];

    // ---- layer 1: gates = Whh1*h1 + Wx*x + b ----
#pragma unroll
    for (int mb = 0; mb < 4; ++mb) {
      const int p = 16*mb + cl;
      const f16x8 ax  = *(const f16x8*)(xsr + p*40 + qd*8);
      const f16x8 ah0 = *(const f16x8*)(h1r + p*72 + qd*8);
      const f16x8 ah1 = *(const f16x8*)(h1r + p*72 + 32 + qd*8);
      f32x4 acc[4];
#pragma unroll
      for (int P = 0; P < 4; ++P) {
        acc[P] = (f32x4){ bxr[P], bxr[P], bxr[P], bxr[P] };
        mfma_agf(acc[P], ah0, whh1a[P][0]);
        mfma_ag (acc[P], ah1, whh1a[P][1]);
        acc[P] = __builtin_amdgcn_mfma_f32_16x16x32_f16(ax, wxf[P], acc[P], 0, 0, 0);
      }
#pragma unroll
      for (int r = 0; r < 4; ++r) {
        const float ig = sig_pre(acc[0][r]);
        const float fg = sig_pre(acc[1][r]);
        const float gg = tanh_pre(acc[2][r]);
        const float og = sig_pre(acc[3][r]);
        const float cn = fg * c1s[mb][r] + ig * gg;
        c1s[mb][r] = cn;
        const float hn = og * tanh_raw(cn);
        h1w[(16*mb + 4*qd + r)*72 + 16*wv + cl] = (f16)hn;
      }
    }
    __syncthreads();

    // ---- layer 2: gates = W21*h1_new + Whh2*h2 + b ----
#pragma unroll
    for (int mb = 0; mb < 4; ++mb) {
      const int p = 16*mb + cl;
      const f16x8 an0 = *(const f16x8*)(h1w + p*72 + qd*8);
      const f16x8 an1 = *(const f16x8*)(h1w + p*72 + 32 + qd*8);
      const f16x8 a20 = *(const f16x8*)(h2r + p*72 + qd*8);
      const f16x8 a21 = *(const f16x8*)(h2r + p*72 + 32 + qd*8);
      f32x4 acc[4];
#pragma unroll
      for (int P = 0; P < 4; ++P) {
        acc[P] = (f32x4){ b2r[P], b2r[P], b2r[P], b2r[P] };
        mfma_agf(acc[P], an0, w21a[P][0]);
        mfma_ag (acc[P], an1, w21a[P][1]);
        mfma_ag (acc[P], a20, whh2a[P]);
        acc[P] = __builtin_amdgcn_mfma_f32_16x16x32_f16(a21, whh2v[P], acc[P], 0, 0, 0);
      }
#pragma unroll
      for (int r = 0; r < 4; ++r) {
        const float ig = sig_pre(acc[0][r]);
        const float fg = sig_pre(acc[1][r]);
        const float gg = tanh_pre(acc[2][r]);
        const float og = sig_pre(acc[3][r]);
        const float co = ag_get(c2s[mb][r]);
        const float cn = fg * co + ig * gg;
        c2s[mb][r] = ag_put(cn);
        const float hn = og * tanh_raw(cn);
        h2w[(16*mb + 4*qd + r)*72 + 16*wv + cl] = (f16)hn;
      }
    }

    // ---- store prefetched x_{t+1}: one ds_write_b128 ----
    if (t + 1 < TT) {
      f16* xsw = xs[(t + 1) & 1];
      f16x8 v;
#pragma unroll
      for (int j = 0; j < 8; ++j) v[j] = (f16)xr[j];
      *(f16x8*)(xsw + sp*40 + cb) = v;
    }
    __syncthreads();
  }

  // ---- head epilogue: out[p] = bhead + sum_k h2[p][k] * wh[k] ----
  if (tid < 64) {
    const float* wh = (const float*)(ws + WS_WH);
    const f16* row = &h2buf[0][tid * 72];   // final h2 lives in buffer 0
    float s = *((const float*)(ws + WS_BH));
#pragma unroll
    for (int k = 0; k < 64; ++k) s += (float)row[k] * wh[k];
    out[gpix + tid] = s;
  }
}

extern "C" void kernel_launch(void* const* d_in, const int* in_sizes, int n_in,
                              void* d_out, int out_size, void* d_ws, size_t ws_size,
                              hipStream_t stream) {
  const float* x      = (const float*)d_in[0];
  const float* W_red  = (const float*)d_in[1];
  const float* b_red  = (const float*)d_in[2];
  const float* Wih1   = (const float*)d_in[3];
  const float* Whh1   = (const float*)d_in[4];
  const float* bih1   = (const float*)d_in[5];
  const float* bhh1   = (const float*)d_in[6];
  const float* Wc1    = (const float*)d_in[7];
  const float* bc1    = (const float*)d_in[8];
  const float* Wih2   = (const float*)d_in[9];
  const float* Whh2   = (const float*)d_in[10];
  const float* bih2   = (const float*)d_in[11];
  const float* bhh2   = (const float*)d_in[12];
  const float* Wc2    = (const float*)d_in[13];
  const float* bc2    = (const float*)d_in[14];
  const float* W_head = (const float*)d_in[15];
  const float* b_head = (const float*)d_in[16];

  prep_kernel<<<256, 64, 0, stream>>>(W_red, b_red, Wih1, Whh1, bih1, bhh1,
                                      Wc1, bc1, Wih2, Whh2, bih2, bhh2,
                                      Wc2, bc2, W_head, b_head,
                                      (unsigned char*)d_ws);
  convlstm_main<<<2048, 256, 0, stream>>>(x, (const unsigned char*)d_ws,
                                          (float*)d_out);
}

// Round 5
// 377.714 us; speedup vs baseline: 1.9812x; 1.0352x over previous
//
#include <hip/hip_runtime.h>

typedef _Float16 f16;
typedef _Float16 f16x8 __attribute__((ext_vector_type(8)));
typedef float f32x4 __attribute__((ext_vector_type(4)));

#define CIN 28
#define TT 8
#define HW 16384

// gate pre-scales folded into weights: i,f,o rows scaled by -log2e so
// E=exp2(acc)=e^{-x} and sig(x)=1/(1+E); g rows scaled by +2log2e so
// E=exp2(acc)=e^{2x} and tanh(x)=(E-1)/(E+1).
#define S_SIG  (-1.44269504088896341f)
#define S_TANH ( 2.88539008177792681f)

// workspace layout (bytes)
#define WS_WX    0        // f16 [256][32]  folded Wih1*W_red (+denorm scales, gate scale)
#define WS_WHH1  16384    // f16 [256][64]
#define WS_W21   49152    // f16 [256][64]  folded Wih2*Wc1
#define WS_WHH2  81920    // f16 [256][64]
#define WS_BX    114688   // f32 [256]
#define WS_B2    115712   // f32 [256]
#define WS_WH    116736   // f32 [64]       folded W_head*Wc2
#define WS_BH    116992   // f32 [1]

// Fused LSTM cell activation: 5 exp2 + 3 rcp (was 10 transcendentals).
// sig(i)*tanh(g) = (Eg-1)*rcp((1+Ei)(1+Eg)); sig(o)*tanh(c) likewise.
__device__ __forceinline__ float lstm_act(float gi, float gf, float gg, float go,
                                          float& c) {
  const float Ei = __builtin_amdgcn_exp2f(gi);
  const float Ef = __builtin_amdgcn_exp2f(gf);
  const float Eg = __builtin_amdgcn_exp2f(gg);
  const float Eo = __builtin_amdgcn_exp2f(go);
  const float rig = __builtin_amdgcn_rcpf((1.f + Ei) * (1.f + Eg));
  const float rf  = __builtin_amdgcn_rcpf(1.f + Ef);
  const float cn  = __builtin_fmaf(rf, c, (Eg - 1.f) * rig);
  c = cn;
  const float Ec  = __builtin_amdgcn_exp2f(cn * S_TANH);
  const float roc = __builtin_amdgcn_rcpf((1.f + Eo) * (1.f + Ec));
  return (Ec - 1.f) * roc;
}

// MFMA with B operand pinned in AGPRs (frees arch VGPRs; gfx950 unified file).
// First-of-chain variant has s_nop for the VALU-write -> MFMA-read-C hazard
// (inline asm is opaque to the hazard recognizer). The LAST mfma of every
// accumulation chain is the __builtin (VGPR B) so the compiler handles the
// MFMA -> VALU-read-of-acc hazard itself.
__device__ __forceinline__ void mfma_agf(f32x4& c, f16x8 a, f16x8 b) {
  asm("s_nop 1\n\tv_mfma_f32_16x16x32_f16 %0, %1, %2, %0"
      : "+v"(c) : "v"(a), "a"(b));
}
__device__ __forceinline__ void mfma_ag(f32x4& c, f16x8 a, f16x8 b) {
  asm("v_mfma_f32_16x16x32_f16 %0, %1, %2, %0"
      : "+v"(c) : "v"(a), "a"(b));
}
// AGPR-resident scalar state (c2) helpers
__device__ __forceinline__ float ag_get(float a) {
  float v; asm("v_accvgpr_read_b32 %0, %1" : "=v"(v) : "a"(a)); return v;
}
__device__ __forceinline__ float ag_put(float v) {
  float a; asm("v_accvgpr_write_b32 %0, %1" : "=a"(a) : "v"(v)); return a;
}

// Parallel prep: 256 blocks (one per gate row g) x 64 threads (one per k).
__global__ __launch_bounds__(64) void prep_kernel(
    const float* __restrict__ W_red, const float* __restrict__ b_red,
    const float* __restrict__ Wih1, const float* __restrict__ Whh1,
    const float* __restrict__ bih1, const float* __restrict__ bhh1,
    const float* __restrict__ Wc1,  const float* __restrict__ bc1,
    const float* __restrict__ Wih2, const float* __restrict__ Whh2,
    const float* __restrict__ bih2, const float* __restrict__ bhh2,
    const float* __restrict__ Wc2,  const float* __restrict__ bc2,
    const float* __restrict__ W_head, const float* __restrict__ b_head,
    unsigned char* __restrict__ ws)
{
  const int g = blockIdx.x;    // 0..255 gate row
  const int k = threadIdx.x;   // 0..63
  f16* WxH   = (f16*)(ws + WS_WX);
  f16* Whh1H = (f16*)(ws + WS_WHH1);
  f16* W21H  = (f16*)(ws + WS_W21);
  f16* Whh2H = (f16*)(ws + WS_WHH2);
  float* BX  = (float*)(ws + WS_BX);
  float* B2  = (float*)(ws + WS_B2);
  float* WHp = (float*)(ws + WS_WH);
  float* BHp = (float*)(ws + WS_BH);

  const float sc = ((g >> 6) == 2) ? S_TANH : S_SIG;  // gate g uses tanh

  // Wx[g][k] = Wih1[g,:] @ W_red[:,k]  (k < CIN), + u/v denorm fold
  float wxv = 0.f;
  if (k < CIN) {
    float s = 0.f;
    for (int r = 0; r < 24; ++r) s += Wih1[g*24 + r] * W_red[r*28 + k];
    wxv = s;
  }
  const float wx11 = __shfl(wxv, 11, 64);   // pre-scale values for bias fold
  const float wx12 = __shfl(wxv, 12, 64);
  if (k == 11) wxv *= 0.15f;                // SD_U
  if (k == 12) wxv *= 0.12f;                // SD_V
  if (k < 32) WxH[g*32 + k] = (f16)(wxv * sc);

  Whh1H[g*64 + k] = (f16)(Whh1[g*64 + k] * sc);
  Whh2H[g*64 + k] = (f16)(Whh2[g*64 + k] * sc);

  // W21[g][k] = Wih2[g,:] @ Wc1[:,k]   (Wih2 row broadcast, Wc1 coalesced)
  {
    float s = 0.f;
    for (int m = 0; m < 64; ++m) s += Wih2[g*64 + m] * Wc1[m*64 + k];
    W21H[g*64 + k] = (f16)(s * sc);
  }

  if (k == 0) {
    float bx = bih1[g] + bhh1[g];
    for (int r = 0; r < 24; ++r) bx += Wih1[g*24 + r] * b_red[r];
    bx += wx11 * 0.02f + wx12 * (-0.01f);   // MU_U, MU_V
    BX[g] = bx * sc;
    float b2v = bih2[g] + bhh2[g];
    for (int m = 0; m < 64; ++m) b2v += Wih2[g*64 + m] * bc1[m];
    B2[g] = b2v * sc;
  }
  if (g == 0) {
    float s = 0.f;
    for (int m = 0; m < 64; ++m) s += W_head[m] * Wc2[m*64 + k];
    WHp[k] = s;
    if (k == 0) {
      float s2 = b_head[0];
      for (int m = 0; m < 64; ++m) s2 += W_head[m] * bc2[m];
      BHp[0] = s2;
    }
  }
}

// 64 pixels/block, 4 waves; wave w owns hidden cols [16w,16w+16) x all 4
// gates for all 64 pixels. Recurrent weight B-frags: whh1[0..1], w21[0..1],
// whh2[0] in AGPRs (inline-asm MFMA), wx + whh2[1] in VGPRs (builtin MFMA,
// last of each chain). c2 state in AGPRs. Arch-VGPR demand ~115 < 128 cap.
__global__ __launch_bounds__(256)
__attribute__((amdgpu_waves_per_eu(2, 2)))
void convlstm_main(
    const float* __restrict__ x, const unsigned char* __restrict__ ws,
    float* __restrict__ out)
{
  __shared__ __align__(16) f16 xs[2][64 * 40];       // [pixel][ch], stride 40
  __shared__ __align__(16) f16 h1buf[2][64 * 72];    // [pixel][hid], stride 72
  __shared__ __align__(16) f16 h2buf[2][64 * 72];

  const int tid  = threadIdx.x;
  const int lane = tid & 63;
  const int wv   = tid >> 6;     // wave 0..3
  const int cl   = lane & 15;    // MFMA "lane&15"
  const int qd   = lane >> 4;    // MFMA quad

  const f16* WxG   = (const f16*)(ws + WS_WX);
  const f16* Whh1G = (const f16*)(ws + WS_WHH1);
  const f16* W21G  = (const f16*)(ws + WS_W21);
  const f16* Whh2G = (const f16*)(ws + WS_WHH2);
  const float* BX  = (const float*)(ws + WS_BX);
  const float* B2  = (const float*)(ws + WS_B2);

  // ---- weight fragments (B layout: [n=gate-slice][k]) ----
  f16x8 wxf[4], whh2v[4];                 // VGPR-resident (chain-enders)
  f16x8 whh1a[4][2], w21a[4][2], whh2a[4]; // AGPR-resident (asm-only uses)
  float bxr[4], b2r[4];
#pragma unroll
  for (int P = 0; P < 4; ++P) {                      // i,f,g,o
    const int gr = 64*P + 16*wv + cl;
    wxf[P] = *(const f16x8*)(WxG + gr*32 + qd*8);
    whh1a[P][0] = *(const f16x8*)(Whh1G + gr*64 + qd*8);
    whh1a[P][1] = *(const f16x8*)(Whh1G + gr*64 + 32 + qd*8);
    w21a[P][0]  = *(const f16x8*)(W21G  + gr*64 + qd*8);
    w21a[P][1]  = *(const f16x8*)(W21G  + gr*64 + 32 + qd*8);
    whh2a[P]    = *(const f16x8*)(Whh2G + gr*64 + qd*8);
    whh2v[P]    = *(const f16x8*)(Whh2G + gr*64 + 32 + qd*8);
    bxr[P] = BX[gr];
    b2r[P] = B2[gr];
  }

  // zero t=0 h buffers
  {
    unsigned* z1 = (unsigned*)&h1buf[0][0];
    unsigned* z2 = (unsigned*)&h2buf[0][0];
#pragma unroll
    for (int i = tid; i < 2304; i += 256) { z1[i] = 0u; z2[i] = 0u; }
  }

  const int gpix = blockIdx.x * 64;
  const float* xb = x + (size_t)(gpix >> 14) * (TT * CIN * HW) + (gpix & (HW - 1));

  const int sp = lane;        // staging pixel
  const int cb = wv * 8;      // staging channel base: 0,8,16,24

  // stage x_0: one f16x8 (ds_write_b128) per thread
  {
    f16x8 v;
#pragma unroll
    for (int j = 0; j < 8; ++j) {
      const int ch = cb + j;
      v[j] = (ch < CIN) ? (f16)xb[ch*HW + sp] : (f16)0.f;
    }
    *(f16x8*)(&xs[0][sp*40 + cb]) = v;
  }
  __syncthreads();

  float c1s[4][4];   // VGPR
  float c2s[4][4];   // AGPR-homed (ag_get/ag_put only)
#pragma unroll
  for (int a = 0; a < 4; ++a)
#pragma unroll
    for (int b = 0; b < 4; ++b) { c1s[a][b] = 0.f; c2s[a][b] = ag_put(0.f); }

#pragma unroll 1
  for (int t = 0; t < TT; ++t) {
    // ---- prefetch x_{t+1} into registers (consumed after layer-1 barrier) ----
    float xr[8];
    if (t + 1 < TT) {
      const float* xt = xb + (size_t)(t + 1) * (CIN * HW);
#pragma unroll
      for (int j = 0; j < 8; ++j) {
        const int ch = cb + j;
        xr[j] = (ch < CIN) ? xt[ch*HW + sp] : 0.f;
      }
    }

    const f16* xsr = xs[t & 1];
    const f16* h1r = h1buf[t & 1];
    const f16* h2r = h2buf[t & 1];
    f16* h1w = h1buf[(t + 1) & 1];
    f16* h2w = h2buf[(t + 1) & 1];

    // ---- layer 1: gates = Whh1*h1 + Wx*x + b ----
#pragma unroll
    for (int mb = 0; mb < 4; ++mb) {
      const int p = 16*mb + cl;
      const f16x8 ax  = *(const f16x8*)(xsr + p*40 + qd*8);
      const f16x8 ah0 = *(const f16x8*)(h1r + p*72 + qd*8);
      const f16x8 ah1 = *(const f16x8*)(h1r + p*72 + 32 + qd*8);
      f32x4 acc[4];
#pragma unroll
      for (int P = 0; P < 4; ++P) {
        acc[P] = (f32x4){ bxr[P], bxr[P], bxr[P], bxr[P] };
        mfma_agf(acc[P], ah0, whh1a[P][0]);
        mfma_ag (acc[P], ah1, whh1a[P][1]);
        acc[P] = __builtin_amdgcn_mfma_f32_16x16x32_f16(ax, wxf[P], acc[P], 0, 0, 0);
      }
#pragma unroll
      for (int r = 0; r < 4; ++r) {
        const float hn = lstm_act(acc[0][r], acc[1][r], acc[2][r], acc[3][r],
                                  c1s[mb][r]);
        h1w[(16*mb + 4*qd + r)*72 + 16*wv + cl] = (f16)hn;
      }
    }
    __syncthreads();

    // ---- store prefetched x_{t+1}: overlaps layer-2 MFMA (LDS-write pipe) ----
    if (t + 1 < TT) {
      f16* xsw = xs[(t + 1) & 1];
      f16x8 v;
#pragma unroll
      for (int j = 0; j < 8; ++j) v[j] = (f16)xr[j];
      *(f16x8*)(xsw + sp*40 + cb) = v;
    }

    // ---- layer 2: gates = W21*h1_new + Whh2*h2 + b ----
#pragma unroll
    for (int mb = 0; mb < 4; ++mb) {
      const int p = 16*mb + cl;
      const f16x8 an0 = *(const f16x8*)(h1w + p*72 + qd*8);
      const f16x8 an1 = *(const f16x8*)(h1w + p*72 + 32 + qd*8);
      const f16x8 a20 = *(const f16x8*)(h2r + p*72 + qd*8);
      const f16x8 a21 = *(const f16x8*)(h2r + p*72 + 32 + qd*8);
      f32x4 acc[4];
#pragma unroll
      for (int P = 0; P < 4; ++P) {
        acc[P] = (f32x4){ b2r[P], b2r[P], b2r[P], b2r[P] };
        mfma_agf(acc[P], an0, w21a[P][0]);
        mfma_ag (acc[P], an1, w21a[P][1]);
        mfma_ag (acc[P], a20, whh2a[P]);
        acc[P] = __builtin_amdgcn_mfma_f32_16x16x32_f16(a21, whh2v[P], acc[P], 0, 0, 0);
      }
#pragma unroll
      for (int r = 0; r < 4; ++r) {
        float co = ag_get(c2s[mb][r]);
        const float hn = lstm_act(acc[0][r], acc[1][r], acc[2][r], acc[3][r], co);
        c2s[mb][r] = ag_put(co);
        h2w[(16*mb + 4*qd + r)*72 + 16*wv + cl] = (f16)hn;
      }
    }
    __syncthreads();
  }

  // ---- head epilogue: out[p] = bhead + sum_k h2[p][k] * wh[k] ----
  if (tid < 64) {
    const float* wh = (const float*)(ws + WS_WH);
    const f16* row = &h2buf[0][tid * 72];   // final h2 lives in buffer 0
    float s = *((const float*)(ws + WS_BH));
#pragma unroll
    for (int k = 0; k < 64; ++k) s += (float)row[k] * wh[k];
    out[gpix + tid] = s;
  }
}

extern "C" void kernel_launch(void* const* d_in, const int* in_sizes, int n_in,
                              void* d_out, int out_size, void* d_ws, size_t ws_size,
                              hipStream_t stream) {
  const float* x      = (const float*)d_in[0];
  const float* W_red  = (const float*)d_in[1];
  const float* b_red  = (const float*)d_in[2];
  const float* Wih1   = (const float*)d_in[3];
  const float* Whh1   = (const float*)d_in[4];
  const float* bih1   = (const float*)d_in[5];
  const float* bhh1   = (const float*)d_in[6];
  const float* Wc1    = (const float*)d_in[7];
  const float* bc1    = (const float*)d_in[8];
  const float* Wih2   = (const float*)d_in[9];
  const float* Whh2   = (const float*)d_in[10];
  const float* bih2   = (const float*)d_in[11];
  const float* bhh2   = (const float*)d_in[12];
  const float* Wc2    = (const float*)d_in[13];
  const float* bc2    = (const float*)d_in[14];
  const float* W_head = (const float*)d_in[15];
  const float* b_head = (const float*)d_in[16];

  prep_kernel<<<256, 64, 0, stream>>>(W_red, b_red, Wih1, Whh1, bih1, bhh1,
                                      Wc1, bc1, Wih2, Whh2, bih2, bhh2,
                                      Wc2, bc2, W_head, b_head,
                                      (unsigned char*)d_ws);
  convlstm_main<<<2048, 256, 0, stream>>>(x, (const unsigned char*)d_ws,
                                          (float*)d_out);
}